// Round 2
// 314.994 us; speedup vs baseline: 1.0542x; 1.0542x over previous
//
#include <hip/hip_runtime.h>

typedef unsigned short u16;
typedef unsigned int u32;
typedef __attribute__((ext_vector_type(8))) short bf16x8;   // 8 bf16 = 4 VGPRs
typedef __attribute__((ext_vector_type(4))) float f32x4;

// ---- ws layout (planar path) ----
// xp bf16 [8][66][66][512] halo-padded NHWC : 35,684,352 B at 0
// yb: 8 u16 lead pad + 2048 chunks x 16776 u16 + 16 u16 trail = 68,714,544 B
//   per (img,o) chunk: plane0 (65x66) @0 sz4296 | plane1 (65x64) @4296 sz4160
//                      plane2 (64x66) @8456 sz4224 | plane3 (64x64) @12680 sz4096
// Hy bf16 [9][256][512] = 2,359,296 B
#define XP_BYTES 35684352
#define YB_BYTES 68714544
#define HY_OFF   (XP_BYTES + YB_BYTES)          // 104,398,896
#define WS_NEED  ((size_t)HY_OFF + 2359296)     // 106,758,192
#define CS 16776                                 // chunk stride (u16)

__device__ inline u16 f2bf(float f) {
  union { float f; unsigned u; } v; v.f = f;
  unsigned r = v.u + 0x7fffu + ((v.u >> 16) & 1u);
  return (u16)(r >> 16);
}

__device__ inline void gl_lds16(const u16* g, u16* l) {
  __builtin_amdgcn_global_load_lds(
      (const __attribute__((address_space(1))) unsigned int*)g,
      (__attribute__((address_space(3))) unsigned int*)l, 16, 0, 0);
}

// ---------------- x prep: f32 NCHW -> bf16 NHWC with 1-px zero halo (self-zeroing) ----------
__global__ void xprep(const float* __restrict__ x, u16* __restrict__ xp) {
  __shared__ float tile[64 * 65];
  int bid = blockIdx.x;
  int cc = bid & 7, h = (bid >> 3) & 63, n = bid >> 9;
  int c0 = cc * 64;
  int t = threadIdx.x;
  const float* xb = x + ((size_t)(n * 512 + c0) * 64 + h) * 64;
  for (int r = 0; r < 16; ++r) {
    int flat = r * 256 + t;
    int ci = flat >> 6, w = flat & 63;
    tile[w * 65 + ci] = xb[(size_t)ci * 4096 + w];
  }
  __syncthreads();
  u16* xpb = xp + ((size_t)(n * 66 + h + 1) * 66 + 1) * 512 + c0;
  for (int r = 0; r < 8; ++r) {
    int flat = r * 256 + t;
    int pr = flat & 31;
    int w = flat >> 5;
    int ci = pr * 2;
    float v0 = tile[w * 65 + ci], v1 = tile[w * 65 + ci + 1];
    unsigned pk = (unsigned)f2bf(v0) | ((unsigned)f2bf(v1) << 16);
    *(unsigned*)(xpb + (size_t)w * 512 + ci) = pk;
  }
  u16* rowbase = xp + ((size_t)(n * 66 + h + 1) * 66) * 512 + c0;
  if (t < 32) *(u32*)(rowbase + 2 * t) = 0u;
  else if (t < 64) *(u32*)(rowbase + (size_t)65 * 512 + 2 * (t - 32)) = 0u;
  if (h == 0) {
    u16* r0 = xp + ((size_t)(n * 66) * 66) * 512 + c0;
    for (int j = t; j < 2112; j += 256) {
      int col = j >> 5, wi = j & 31;
      *(u32*)(r0 + (size_t)col * 512 + 2 * wi) = 0u;
    }
  }
  if (h == 63) {
    u16* r65 = xp + ((size_t)(n * 66 + 65) * 66) * 512 + c0;
    for (int j = t; j < 2112; j += 256) {
      int col = j >> 5, wi = j & 31;
      *(u32*)(r65 + (size_t)col * 512 + 2 * wi) = 0u;
    }
  }
}

// ---------------- weight prep: modulate+demod, 9 conv-transpose tap planes ----------------
__global__ void wprep9(const float* __restrict__ w, u16* __restrict__ Hy) {
  __shared__ float wl[4608];
  __shared__ float red[256];
  int o = blockIdx.x, t = threadIdx.x;
  const float* wo = w + (size_t)o * 4608;
  float s = 0.f;
  for (int j = t; j < 4608; j += 256) { float v = wo[j]; wl[j] = v; s += v * v; }
  red[t] = s;
  __syncthreads();
  for (int st = 128; st; st >>= 1) { if (t < st) red[t] += red[t + st]; __syncthreads(); }
  float demod = rsqrtf(red[0] * (1.0f / 4608.0f) + 1e-6f);
  float scale = demod * 0.014731391274719739f;
  const int DY[9] = {0, 2, 0, 2, 0, 2, 1, 1, 1};
  const int DX[9] = {0, 0, 2, 2, 1, 1, 0, 2, 1};
  for (int i = t; i < 512; i += 256) {
#pragma unroll
    for (int pl = 0; pl < 9; ++pl) {
      float g = wl[i * 9 + DY[pl] * 3 + DX[pl]] * scale;
      Hy[(size_t)pl * 131072 + (size_t)o * 512 + i] = f2bf(g);
    }
  }
}

// ---------------- pass 1: conv-transpose y — 256x256 tile, 8-phase counted-vmcnt schedule --
// 512 thr / 8 waves (2M x 4N); per-wave out 128m x 64o; BK=64; 2 K-tiles per iter.
// LDS 128KiB: buf c in u16 [c*32768, +32768): A 4 issues x 4096, B at +16384 likewise.
// XOR swizzle (proven): LDS(r, ch) = G(r, ch ^ (r&7)) at 16B-chunk granularity; staged via
// pre-swizzled global source (gch), read back with ch = (ks*4+grp) ^ (r&7).
// Phase plan per iteration (tiles t=2it in buf0, t+1 in buf1):
//  ph1 q(0,0) rdA-mi0+rdB-ni0 buf0 | stage A-h0(t+1)->buf1
//  ph2 q(0,1) rdB-ni1 buf0         | stage A-h1(t+1)->buf1
//  ph3 q(1,1) rdA-mi1 buf0         | stage B-h0(t+2)->buf0   (B(t) reads ended ph2)
//  ph4 q(1,0) regs only            | stage B-h1(t+2)->buf0 ; vmcnt(4) [0 on last iter]
//  ph5..ph8 mirror on buf1, staging A(t+2)->buf0 (ph5/6), B(t+3)->buf1 (ph7/8); vmcnt(4) ph8
// Hazard ledger (audited R1):
//  - in-flight: prologue 12 issued, WAITV4 -> tile0 A+B landed, B(t1) in flight.
//    ph4 wait: 4 leftover + 8 issued -> retires A(t+1)+B(t+1)-remnant, leaves B(t+2).
//    ph8 wait: retires A(t+2)+B(t+2), leaves B(t+3). Last iter: WAITV0 at ph4, ph5-8 stage
//    nothing (tile >= NK guard), so epilogue starts drained (extra WAITV0 is defensive).
//  - WAR: every stage lands >=1 barrier after its region's last ds_read (bf0/bf1 are
//    register-held so ph4/ph8 are read-free); reads cannot hoist past inline-asm memory
//    clobbers (WAITL/WAITV), MFMA pinned by sched_barrier(0) after lgkmcnt (rule #18).
//  - barriers: uniform count for all waves (no barrier under divergent control).
#define BARR() __builtin_amdgcn_s_barrier()
#define WAITL() do { asm volatile("s_waitcnt lgkmcnt(0)" ::: "memory"); __builtin_amdgcn_sched_barrier(0); } while (0)
#define WAITV4() do { asm volatile("s_waitcnt vmcnt(4)" ::: "memory"); __builtin_amdgcn_sched_barrier(0); } while (0)
#define WAITV0() do { asm volatile("s_waitcnt vmcnt(0)" ::: "memory"); __builtin_amdgcn_sched_barrier(0); } while (0)

__device__ __forceinline__ void rdA8(const u16* sb, int rbase, int grp, bf16x8 af[4][2]) {
#pragma unroll
  for (int ti = 0; ti < 4; ++ti) {
    int r = rbase + ti * 16;
    int x7 = r & 7;
#pragma unroll
    for (int ks = 0; ks < 2; ++ks) {
      int ch = (ks * 4 + grp) ^ x7;
      af[ti][ks] = *(const bf16x8*)(sb + r * 64 + ch * 8);
    }
  }
}

__device__ __forceinline__ void rdB4(const u16* sb, int rbase, int grp, bf16x8 bfr[2][2]) {
#pragma unroll
  for (int tj = 0; tj < 2; ++tj) {
    int r = rbase + tj * 16;
    int x7 = r & 7;
#pragma unroll
    for (int ks = 0; ks < 2; ++ks) {
      int ch = (ks * 4 + grp) ^ x7;
      bfr[tj][ks] = *(const bf16x8*)(sb + 16384 + r * 64 + ch * 8);
    }
  }
}

template <int MI, int NI>
__device__ __forceinline__ void qmfma(const bf16x8 af[4][2], const bf16x8 bfr[2][2],
                                      f32x4 acc[8][4]) {
#pragma unroll
  for (int ti = 0; ti < 4; ++ti)
#pragma unroll
    for (int tj = 0; tj < 2; ++tj)
#pragma unroll
      for (int ks = 0; ks < 2; ++ks)
        acc[MI * 4 + ti][NI * 2 + tj] = __builtin_amdgcn_mfma_f32_16x16x32_bf16(
            af[ti][ks], bfr[tj][ks], acc[MI * 4 + ti][NI * 2 + tj], 0, 0, 0);
}

__device__ __forceinline__ void stA2(const u16* __restrict__ xp, u16* d0, u16* d1,
                                     int tile, int NK, u32 a0, u32 a1,
                                     u32 adj1, u32 adj2, u32 adj3) {
  if (tile < NK) {
    int tap = tile >> 3;
    u32 ko = (u32)((tile & 7) << 6);
    u32 adj = tap == 0 ? 0u : (tap == 1 ? adj1 : (tap == 2 ? adj2 : adj3));
    gl_lds16(xp + (a0 - adj + ko), d0);
    gl_lds16(xp + (a1 - adj + ko), d1);
  }
}

__device__ __forceinline__ void stB2(const u16* __restrict__ hb, u16* d0, u16* d1,
                                     int tile, int NK, u32 b0, u32 b1) {
  if (tile < NK) {
    int tap = tile >> 3;
    u32 ko = (u32)((tile & 7) << 6);
    const u16* hp = hb + (size_t)tap * 131072;
    gl_lds16(hp + (b0 + ko), d0);
    gl_lds16(hp + (b1 + ko), d1);
  }
}

__global__ __launch_bounds__(512, 2) void conv_y(const u16* __restrict__ xp,
                                                 const u16* __restrict__ Hy,
                                                 u16* __restrict__ yb) {
  __shared__ __align__(16) u16 su[65536];   // 128 KiB: 2 x (A 16K u16 + B 16K u16)

  int bid = blockIdx.x;
  int t = threadIdx.x;
  int wid = t >> 6, lane = t & 63;

  // img -> XCD pinned (8 imgs, 8 XCDs); heavy phases first within each img
  int img = bid & 7;
  int kk = bid >> 3;                       // 0..66
  int mt, Wp, CNT, NTAP, PB, PO, STLIM;
  u32 adj1 = 0, adj2 = 0, adj3 = 0;        // (du*66+dv)*512 per tap (tap0 always 0)
  if (kk < 17)      { mt = kk;      Wp = 66; CNT = 4290; NTAP = 4; PB = 0; PO = 0;     STLIM = 4296;
                      adj1 = 33792u; adj2 = 512u; adj3 = 34304u; }
  else if (kk < 34) { mt = kk - 17; Wp = 64; CNT = 4160; NTAP = 2; PB = 4; PO = 4296;  STLIM = 4160;
                      adj1 = 33792u; }
  else if (kk < 51) { mt = kk - 34; Wp = 66; CNT = 4224; NTAP = 2; PB = 6; PO = 8456;  STLIM = 4224;
                      adj1 = 512u; }
  else              { mt = kk - 51; Wp = 64; CNT = 4096; NTAP = 1; PB = 8; PO = 12680; STLIM = 4096; }

  int m0 = mt * 256;
  int NK = NTAP * 8;                        // K-tiles of 64
  int NITER = NTAP * 4;
  const u16* hb = Hy + (size_t)PB * 131072;

  int wm = wid >> 2, wn = wid & 3;          // 2M x 4N waves
  int la = lane & 15, grp = lane >> 4;

  // staging coords: 512 threads cover 64 rows x 8 chunks per issue; XOR pre-swizzle on source
  int rho = t >> 3;                         // 0..63
  int gch = (t & 7) ^ (rho & 7);

  u32 gA[4], gB[4];
#pragma unroll
  for (int i = 0; i < 4; ++i) {
    int m = m0 + i * 64 + rho;
    if (m > CNT - 1) m = CNT - 1;           // clamp (garbage compute, store-guarded)
    u32 a = (u32)m / (u32)Wp;
    u32 b = (u32)m - a * (u32)Wp;
    gA[i] = (u32)(((img * 66 + a + 1) * 66 + (b + 1)) * 512 + gch * 8);
    gB[i] = (u32)((i * 64 + rho) * 512 + gch * 8);
  }
  u16* sw = su + wid * 512;                 // per-wave staging dest base

  f32x4 acc[8][4];
#pragma unroll
  for (int i = 0; i < 8; ++i)
#pragma unroll
    for (int j = 0; j < 4; ++j) acc[i][j] = (f32x4){0.f, 0.f, 0.f, 0.f};

  // ---- prologue: tile0 (all 4 halves) + B halves of tile1; wait tile0, allow B(1) in flight
  stB2(hb, sw + 16384, sw + 20480, 0, NK, gB[0], gB[1]);
  stB2(hb, sw + 24576, sw + 28672, 0, NK, gB[2], gB[3]);
  stA2(xp, sw, sw + 4096, 0, NK, gA[0], gA[1], adj1, adj2, adj3);
  stA2(xp, sw + 8192, sw + 12288, 0, NK, gA[2], gA[3], adj1, adj2, adj3);
  stB2(hb, sw + 49152, sw + 53248, 1, NK, gB[0], gB[1]);
  stB2(hb, sw + 57344, sw + 61440, 1, NK, gB[2], gB[3]);
  WAITV4();
  BARR();

  bf16x8 af[4][2], bf0[2][2], bf1[2][2];

#pragma unroll 1
  for (int it = 0; it < NITER; ++it) {
    int t0 = 2 * it;
    bool more = (it + 1 < NITER);

    // ---- ph1: buf0 q(0,0) | stage A-h0(t0+1) -> buf1
    rdA8(su, wm * 128 + la, grp, af);
    rdB4(su, wn * 64 + la, grp, bf0);
    stA2(xp, sw + 32768, sw + 36864, t0 + 1, NK, gA[0], gA[1], adj1, adj2, adj3);
    BARR(); WAITL();
    __builtin_amdgcn_s_setprio(1); qmfma<0, 0>(af, bf0, acc); __builtin_amdgcn_s_setprio(0);
    BARR();
    // ---- ph2: q(0,1) | stage A-h1(t0+1) -> buf1
    rdB4(su, wn * 64 + 32 + la, grp, bf1);
    stA2(xp, sw + 40960, sw + 45056, t0 + 1, NK, gA[2], gA[3], adj1, adj2, adj3);
    BARR(); WAITL();
    __builtin_amdgcn_s_setprio(1); qmfma<0, 1>(af, bf1, acc); __builtin_amdgcn_s_setprio(0);
    BARR();
    // ---- ph3: q(1,1) | stage B-h0(t0+2) -> buf0
    rdA8(su, wm * 128 + 64 + la, grp, af);
    stB2(hb, sw + 16384, sw + 20480, t0 + 2, NK, gB[0], gB[1]);
    BARR(); WAITL();
    __builtin_amdgcn_s_setprio(1); qmfma<1, 1>(af, bf1, acc); __builtin_amdgcn_s_setprio(0);
    BARR();
    // ---- ph4: q(1,0) (regs only) | stage B-h1(t0+2) -> buf0 | counted vmcnt
    stB2(hb, sw + 24576, sw + 28672, t0 + 2, NK, gB[2], gB[3]);
    BARR(); WAITL();
    __builtin_amdgcn_s_setprio(1); qmfma<1, 0>(af, bf0, acc); __builtin_amdgcn_s_setprio(0);
    if (more) { WAITV4(); } else { WAITV0(); }
    BARR();
    // ---- ph5: buf1 q(0,0) | stage A-h0(t0+2) -> buf0
    rdA8(su + 32768, wm * 128 + la, grp, af);
    rdB4(su + 32768, wn * 64 + la, grp, bf0);
    stA2(xp, sw, sw + 4096, t0 + 2, NK, gA[0], gA[1], adj1, adj2, adj3);
    BARR(); WAITL();
    __builtin_amdgcn_s_setprio(1); qmfma<0, 0>(af, bf0, acc); __builtin_amdgcn_s_setprio(0);
    BARR();
    // ---- ph6: q(0,1) | stage A-h1(t0+2) -> buf0
    rdB4(su + 32768, wn * 64 + 32 + la, grp, bf1);
    stA2(xp, sw + 8192, sw + 12288, t0 + 2, NK, gA[2], gA[3], adj1, adj2, adj3);
    BARR(); WAITL();
    __builtin_amdgcn_s_setprio(1); qmfma<0, 1>(af, bf1, acc); __builtin_amdgcn_s_setprio(0);
    BARR();
    // ---- ph7: q(1,1) | stage B-h0(t0+3) -> buf1
    rdA8(su + 32768, wm * 128 + 64 + la, grp, af);
    stB2(hb, sw + 49152, sw + 53248, t0 + 3, NK, gB[0], gB[1]);
    BARR(); WAITL();
    __builtin_amdgcn_s_setprio(1); qmfma<1, 1>(af, bf1, acc); __builtin_amdgcn_s_setprio(0);
    BARR();
    // ---- ph8: q(1,0) (regs only) | stage B-h1(t0+3) -> buf1 | counted vmcnt
    stB2(hb, sw + 57344, sw + 61440, t0 + 3, NK, gB[2], gB[3]);
    BARR(); WAITL();
    __builtin_amdgcn_s_setprio(1); qmfma<1, 0>(af, bf0, acc); __builtin_amdgcn_s_setprio(0);
    if (more) { WAITV4(); }
    BARR();
  }

  // ---- epilogue: acc -> LDS [256 o][256 m] (XOR-swizzled chunks), dense bf16x8 stores
  WAITV0();          // defensive drain (ledger says already 0 here)
  __syncthreads();
#pragma unroll
  for (int nj = 0; nj < 4; ++nj) {
    int orow = wn * 64 + nj * 16 + la;
    int x7 = orow & 7;
#pragma unroll
    for (int mi8 = 0; mi8 < 8; ++mi8)
#pragma unroll
      for (int jp = 0; jp < 2; ++jp) {
        int ml = wm * 128 + mi8 * 16 + grp * 4 + jp * 2;
        u32 pk = (u32)f2bf(acc[mi8][nj][jp * 2]) |
                 ((u32)f2bf(acc[mi8][nj][jp * 2 + 1]) << 16);
        *(u32*)(su + orow * 256 + (((ml >> 3) ^ x7) * 8) + (ml & 7)) = pk;
      }
  }
  __syncthreads();
  {
    u16* ybp = yb + 8;
    int o = t >> 1, s = t & 1;
    size_t gb = (size_t)(img * 256 + o) * CS + PO + m0 + s * 128;
    int x7 = o & 7;
#pragma unroll
    for (int i = 0; i < 16; ++i) {
      int mo = s * 128 + i * 8;
      if (m0 + mo < STLIM)
        *(bf16x8*)(ybp + gb + i * 8) = *(const bf16x8*)(su + o * 256 + (((mo >> 3) ^ x7) * 8));
    }
  }
}

// ---------------- pass 2: depthwise FIR on planar y; thread = 4p x 8q z block ----------------
// Derivation (R4 bug fixed): z[p][q] = (1/16) sum f1[s]f1[t] y[p+s-1][q+t-1], f1={1,3,3,1}.
// y-phase row 2a+rp: s = 2a+rp-p+1. With a0 = 2*phb-1, hcol index la -> a = a0+la:
//   rp=0: ip0: 3h[1]+h[2] | ip1: h[1]+3h[2] | ip2: 3h[2]+h[3] | ip3: h[2]+3h[3]
//   rp=1: ip0: h[0]+3h[1] | ip1: 3h[1]+h[2] | ip2: h[1]+3h[2] | ip3: 3h[2]+h[3]
// cols with b0 = 4*qh-1, v index lb -> b = b0+lb, e = jq>>1:
//   rq=0: jq=2e: 3v[e+1]+v[e+2] | jq=2e+1: v[e+1]+3v[e+2]
//   rq=1: jq=2e: v[e]+3v[e+1]   | jq=2e+1: 3v[e+1]+v[e+2]
__global__ void fir2(const u16* __restrict__ yb, float* __restrict__ z) {
  int flat = blockIdx.x * 256 + threadIdx.x;
  int qh = flat & 15, phb = (flat >> 4) & 31, o = (flat >> 9) & 255, n = flat >> 17;
  const u16* cb = yb + 8 + (size_t)(n * 256 + o) * CS;
  int a0 = 2 * phb - 1;
  int b0 = 4 * qh - 1;

  float out[4][8];
#pragma unroll
  for (int i = 0; i < 4; ++i)
#pragma unroll
    for (int j = 0; j < 8; ++j) out[i][j] = 0.f;

  const int PO_[4] = {0, 4296, 8456, 12680};
  const int WP_[4] = {66, 64, 66, 64};
  const int HA_[4] = {65, 65, 64, 64};
  const int WB_[4] = {65, 64, 65, 64};

#pragma unroll
  for (int ph = 0; ph < 4; ++ph) {
    int rp = ph >> 1, rq = ph & 1;
    const u16* pb = cb + PO_[ph];
    float hcol[4][8];
#pragma unroll
    for (int la = 0; la < 4; ++la) {
      if (rp == 0 && la == 0) continue;          // row unused for rp=0 (folds at compile time)
      int ag = a0 + la;
      bool rv = (ag >= 0) && (ag < HA_[ph]);
      const u16* rb = pb + (ag * WP_[ph] + b0 - 1);   // even offset; pads keep it in d_ws
      u32 ls[4];
      ls[0] = *(const u32*)(rb);
      ls[1] = *(const u32*)(rb + 2);
      ls[2] = *(const u32*)(rb + 4);
      ls[3] = *(const u32*)(rb + 6);
      float v[6];
#pragma unroll
      for (int lb = 0; lb < 6; ++lb) {
        int jj = lb + 1;                          // rb[jj] = col b0-1+jj = b0+lb
        u32 w16 = (jj & 1) ? (ls[jj >> 1] >> 16) : (ls[jj >> 1] & 0xffffu);
        float fv = __uint_as_float(w16 << 16);
        int bg = b0 + lb;
        bool ok = rv && (bg >= 0) && (bg < WB_[ph]);
        v[lb] = ok ? fv : 0.f;
      }
#pragma unroll
      for (int e = 0; e < 4; ++e) {
        if (rq == 0) {
          hcol[la][2 * e]     = 3.f * v[e + 1] + v[e + 2];
          hcol[la][2 * e + 1] = v[e + 1] + 3.f * v[e + 2];
        } else {
          hcol[la][2 * e]     = v[e] + 3.f * v[e + 1];
          hcol[la][2 * e + 1] = 3.f * v[e + 1] + v[e + 2];
        }
      }
    }
#pragma unroll
    for (int jq = 0; jq < 8; ++jq) {
      if (rp == 0) {
        out[0][jq] += 3.f * hcol[1][jq] + hcol[2][jq];
        out[1][jq] += hcol[1][jq] + 3.f * hcol[2][jq];
        out[2][jq] += 3.f * hcol[2][jq] + hcol[3][jq];
        out[3][jq] += hcol[2][jq] + 3.f * hcol[3][jq];
      } else {
        out[0][jq] += hcol[0][jq] + 3.f * hcol[1][jq];
        out[1][jq] += 3.f * hcol[1][jq] + hcol[2][jq];
        out[2][jq] += hcol[1][jq] + 3.f * hcol[2][jq];
        out[3][jq] += 3.f * hcol[2][jq] + hcol[3][jq];
      }
    }
  }

  float* zb = z + ((size_t)(n * 256 + o) * 128 + phb * 4) * 128 + qh * 8;
#pragma unroll
  for (int ip = 0; ip < 4; ++ip) {
    f32x4 v0, v1;
#pragma unroll
    for (int j = 0; j < 4; ++j) { v0[j] = out[ip][j] * 0.0625f; v1[j] = out[ip][j + 4] * 0.0625f; }
    *(f32x4*)(zb + (size_t)ip * 128) = v0;
    *(f32x4*)(zb + (size_t)ip * 128 + 4) = v1;
  }
}

// ================= fallback path (R2, proven): FIR-folded fused conv =================
__global__ void wprep36(const float* __restrict__ w, u16* __restrict__ Hm) {
  __shared__ float wl[4608];
  __shared__ float red[256];
  int o = blockIdx.x, t = threadIdx.x;
  const float* wo = w + (size_t)o * 4608;
  float s = 0.f;
  for (int j = t; j < 4608; j += 256) { float v = wo[j]; wl[j] = v; s += v * v; }
  red[t] = s;
  __syncthreads();
  for (int st = 128; st; st >>= 1) { if (t < st) red[t] += red[t + st]; __syncthreads(); }
  float demod = rsqrtf(red[0] * (1.0f / 4608.0f) + 1e-6f);
  float scale = demod * 0.014731391274719739f;
  const float F1[4] = {1.f, 3.f, 3.f, 1.f};
  for (int i = t; i < 512; i += 256) {
    float wm[9];
    for (int k = 0; k < 9; ++k) wm[k] = wl[i * 9 + k] * scale;
    for (int rp = 0; rp < 2; ++rp)
      for (int rq = 0; rq < 2; ++rq)
        for (int u = 0; u < 3; ++u)
          for (int v = 0; v < 3; ++v) {
            int s_ = 2 - 2 * u + rp, t_ = 2 - 2 * v + rq;
            float g = 0.f;
            for (int dy = 0; dy < 3; ++dy) {
              int a = dy + 1 - s_;
              if (a < 0 || a > 3) continue;
              for (int dx = 0; dx < 3; ++dx) {
                int b = dx + 1 - t_;
                if (b < 0 || b > 3) continue;
                g += wm[dy * 3 + dx] * (F1[a] * F1[b]);
              }
            }
            g *= 0.0625f;
            Hm[(size_t)((rp * 2 + rq) * 9 + u * 3 + v) * 131072 + (size_t)o * 512 + i] = f2bf(g);
          }
  }
}

__global__ __launch_bounds__(256) void conv_main(const u16* __restrict__ xp,
                                                 const u16* __restrict__ Hm,
                                                 float* __restrict__ z) {
  __shared__ __align__(16) float smemf[8448];
  u16* su = (u16*)smemf;
  int bid = blockIdx.x;
  int sub = bid & 7;
  int rp = sub >> 2;
  int o0 = (sub & 3) * 64;
  int mtile = bid >> 3;
  int n_img = mtile >> 5;
  int hp0 = (mtile & 31) * 2;
  int t = threadIdx.x;
  int wave = t >> 6, lane = t & 63;
  int wm0 = (wave & 1) * 64;
  int wn0 = (wave >> 1) * 32;
  int la = lane & 15;
  int ks = (lane >> 4) * 8;
  int rsel = t >> 2;
  int koff = (t & 3) * 8;
  f32x4 acc[2][4][2];
#pragma unroll
  for (int a = 0; a < 2; ++a)
#pragma unroll
    for (int b = 0; b < 4; ++b)
#pragma unroll
      for (int c = 0; c < 2; ++c)
        acc[a][b][c] = (f32x4){0.f, 0.f, 0.f, 0.f};
#pragma unroll 1
  for (int tap = 0; tap < 9; ++tap) {
    int du = tap / 3, dv = tap - du * 3;
    const u16* gA0 = xp + ((size_t)(n_img * 66 + hp0 + du) * 66 + dv) * 512;
    const u16* gB0 = Hm + (size_t)(rp * 18 + tap) * 131072 + (size_t)(o0 + rsel) * 512 + koff;
    const u16* gAr0 = gA0 + (size_t)rsel * 512 + koff;
    const u16* gAr1 = gA0 + (size_t)(66 + rsel) * 512 + koff;
#pragma unroll 1
    for (int kc = 0; kc < 16; ++kc) {
      int c0 = kc * 32;
      __syncthreads();
      gl_lds16(gAr0 + c0, su + wave * 512);
      gl_lds16(gAr1 + c0, su + 2048 + wave * 512);
      gl_lds16(gB0 + c0,              su + 4096 + wave * 512);
      gl_lds16(gB0 + 9 * 131072 + c0, su + 6144 + wave * 512);
      __syncthreads();
      bf16x8 af[4];
#pragma unroll
      for (int ti = 0; ti < 4; ++ti)
        af[ti] = *(const bf16x8*)(su + (wm0 + ti * 16 + la) * 32 + ks);
      bf16x8 bfr[2][2];
#pragma unroll
      for (int rqq = 0; rqq < 2; ++rqq)
#pragma unroll
        for (int tj = 0; tj < 2; ++tj)
          bfr[rqq][tj] = *(const bf16x8*)(su + 4096 + rqq * 2048 + (wn0 + tj * 16 + la) * 32 + ks);
#pragma unroll
      for (int rqq = 0; rqq < 2; ++rqq)
#pragma unroll
        for (int ti = 0; ti < 4; ++ti)
#pragma unroll
          for (int tj = 0; tj < 2; ++tj)
            acc[rqq][ti][tj] = __builtin_amdgcn_mfma_f32_16x16x32_bf16(
                af[ti], bfr[rqq][tj], acc[rqq][ti][tj], 0, 0, 0);
    }
  }
  __syncthreads();
  float* lws = smemf + wave * 2112;
  int p = 2 * (hp0 + (wave & 1)) + rp;
#pragma unroll
  for (int tj = 0; tj < 2; ++tj) {
#pragma unroll
    for (int rqq = 0; rqq < 2; ++rqq)
#pragma unroll
      for (int ti = 0; ti < 4; ++ti) {
        int wqb = ti * 16 + (lane >> 4) * 4;
        f32x4 v = acc[rqq][ti][tj];
#pragma unroll
        for (int r = 0; r < 4; ++r)
          lws[la * 132 + 2 * (wqb + r) + rqq] = v[r];
      }
    __syncthreads();
    int obase = o0 + wn0 + tj * 16;
#pragma unroll
    for (int c = 0; c < 8; ++c) {
      int idx = c * 64 + lane;
      int ol = idx >> 5, q4 = (idx & 31) * 4;
      f32x4 vv = *(const f32x4*)(lws + ol * 132 + q4);
      *(f32x4*)(z + (((size_t)n_img * 256 + obase + ol) * 128 + p) * 128 + q4) = vv;
    }
    __syncthreads();
  }
}

extern "C" void kernel_launch(void* const* d_in, const int* in_sizes, int n_in,
                              void* d_out, int out_size, void* d_ws, size_t ws_size,
                              hipStream_t stream) {
  const float* x = (const float*)d_in[0];
  const float* w = (const float*)d_in[1];
  float* z = (float*)d_out;
  u16* xp = (u16*)d_ws;

  if (ws_size >= WS_NEED) {
    u16* yb = (u16*)((char*)d_ws + XP_BYTES);
    u16* hy = (u16*)((char*)d_ws + HY_OFF);
    xprep<<<4096, 256, 0, stream>>>(x, xp);       // self-zeroing xp halos; no memset needed
    wprep9<<<256, 256, 0, stream>>>(w, hy);
    conv_y<<<536, 512, 0, stream>>>(xp, hy, yb);  // 8 img x 67 tiles, img->XCD pinned
    fir2<<<4096, 256, 0, stream>>>(yb, z);
  } else {
    u16* Hm = (u16*)((char*)d_ws + XP_BYTES);
    hipMemsetAsync(xp, 0, XP_BYTES, stream);
    xprep<<<4096, 256, 0, stream>>>(x, xp);
    wprep36<<<256, 256, 0, stream>>>(w, Hm);
    conv_main<<<2048, 256, 0, stream>>>(xp, Hm, z);
  }
}